// Round 3
// baseline (26238.760 us; speedup 1.0000x reference)
//
#include <hip/hip_runtime.h>
#include <hip/hip_cooperative_groups.h>
#include <cstdint>
#include <cstddef>

namespace cg = cooperative_groups;

#define BB 32
#define HH 512
#define EE 256
#define VV 32000
#define TT 64
#define KDIM 1280    // 2H+E
#define NBV 1000     // 32-row vocab tiles
#define NGJ 128      // gates jobs
#define GSTR 2304    // per-wave LDS stride, gates/pre phases (floats)
#define LSTR 1216    // per-wave LDS stride, logits phase (floats)
#define LDSF 9216    // block LDS (floats) = 36.9 KB -> 4 blocks/CU

struct P {
    const int* y0; const float* h0; const float* c0; const float* emb;
    const float* Wih; const float* Whh; const float* bih; const float* bhh;
    const float* Wout; const float* bout;
    float* out; float* staged; int use_staged;
    float* fA; float* fB; float* cA; float* cB; float* gzT;
    float* apv; int* api;
};

__device__ __forceinline__ float sigf(float x) { return 1.0f / (1.0f + expf(-x)); }

// ---------------------------------------------------------------------------
// init: 64 jobs x 256 thr. featT z-region and h-region = h0; cA = c0.
// featT layout: featT[k*32 + b].
// ---------------------------------------------------------------------------
__device__ __forceinline__ void init_job(const P& p, int job, int tid) {
    int idx = job * 256 + tid;
    int kk = idx >> 5;
    int b = idx & 31;
    float zv = p.h0[b * HH + kk];
    p.fA[kk * BB + b] = zv;
    p.fB[kk * BB + b] = zv;
    p.fA[(768 + kk) * BB + b] = zv;
    p.fB[(768 + kk) * BB + b] = zv;
    p.cA[b * HH + kk] = p.c0[b * HH + kk];
}

// ---------------------------------------------------------------------------
// pre: 32 jobs. gzT[j*32+b] = Wih[j][0:512] . z[b] + bih[j] + bhh[j].
// ---------------------------------------------------------------------------
__device__ void pre_job(const P& p, int job, float* lds, int tid, int l, int wu) {
    const int j0 = job * 64;
    const int js = l & 15;
    const int bg = l >> 4;
    float* R = &lds[wu * GSTR];
    float acc[4][8];
#pragma unroll
    for (int i = 0; i < 4; ++i)
#pragma unroll
        for (int q = 0; q < 8; ++q) acc[i][q] = 0.f;

    for (int ch = 0; ch < 4; ++ch) {
        int kg0 = wu * 128 + ch * 32;
#pragma unroll
        for (int i = 0; i < 8; ++i) {
            int f4 = i * 64 + l;
            int r = f4 >> 3;
            int c4 = (f4 & 7) * 4;
            float4 w = *(const float4*)&p.Wih[(size_t)(j0 + r) * 768 + kg0 + c4];
            R[(c4 + 0) * 68 + r] = w.x;
            R[(c4 + 1) * 68 + r] = w.y;
            R[(c4 + 2) * 68 + r] = w.z;
            R[(c4 + 3) * 68 + r] = w.w;
        }
#pragma unroll 4
        for (int kk = 0; kk < 32; ++kk) {
            float4 wv = *(const float4*)&R[kk * 68 + js * 4];
            const float* fp = &p.fA[(kg0 + kk) * BB + bg * 8];
            float4 fa = *(const float4*)fp;
            float4 fb = *(const float4*)(fp + 4);
            float w4[4] = {wv.x, wv.y, wv.z, wv.w};
            float f8[8] = {fa.x, fa.y, fa.z, fa.w, fb.x, fb.y, fb.z, fb.w};
#pragma unroll
            for (int i = 0; i < 4; ++i)
#pragma unroll
                for (int q = 0; q < 8; ++q) acc[i][q] = fmaf(w4[i], f8[q], acc[i][q]);
        }
    }
#pragma unroll
    for (int i = 0; i < 4; ++i) {
        int r = js * 4 + i;
        *(float4*)&R[r * 36 + bg * 8] = make_float4(acc[i][0], acc[i][1], acc[i][2], acc[i][3]);
        *(float4*)&R[r * 36 + bg * 8 + 4] = make_float4(acc[i][4], acc[i][5], acc[i][6], acc[i][7]);
    }
    __syncthreads();
    {
        int j = tid >> 2;
        int bq = (tid & 3) * 8;
        float bias = p.bih[j0 + j] + p.bhh[j0 + j];
#pragma unroll
        for (int q = 0; q < 8; ++q) {
            float s = lds[0 * GSTR + j * 36 + bq + q] + lds[1 * GSTR + j * 36 + bq + q] +
                      lds[2 * GSTR + j * 36 + bq + q] + lds[3 * GSTR + j * 36 + bq + q];
            p.gzT[(size_t)(j0 + j) * BB + bq + q] = s + bias;
        }
    }
    __syncthreads();
}

// ---------------------------------------------------------------------------
// gates: 128 jobs. uc=job>>2 (16 u of 512), bg4=job&3 (8 b). Finalize argmax
// (t>0) or read y0; gates = gz + Wih[:,512:]*emb[y] + Whh*h; LSTM cell;
// writes cNext + fNext h-region; uc==0 also writes fNext emb-region.
// ---------------------------------------------------------------------------
__device__ void gates_job(const P& p, int t, int job, float* lds, int tid, int l, int wu) {
    const float* fCur = (t & 1) ? p.fB : p.fA;
    float* fNext = (t & 1) ? p.fA : p.fB;
    const float* cCur = (t & 1) ? p.cB : p.cA;
    float* cNext = (t & 1) ? p.cA : p.cB;
    const int uc = job >> 2;
    const int b0 = (job & 3) * 8;
    const int js = l & 15;
    const int bg = l >> 4;

    int yv0, yv1, yv2, yv3, yv4, yv5, yv6, yv7;
    if (t == 0) {
        yv0 = p.y0[b0 + 0]; yv1 = p.y0[b0 + 1]; yv2 = p.y0[b0 + 2]; yv3 = p.y0[b0 + 3];
        yv4 = p.y0[b0 + 4]; yv5 = p.y0[b0 + 5]; yv6 = p.y0[b0 + 6]; yv7 = p.y0[b0 + 7];
    } else {
        int bi = l >> 3;
        float best = -3.4e38f;
        int bidx = 0x7fffffff;
        for (int e = (l & 7); e < NBV; e += 8) {
            float v = p.apv[(b0 + bi) * NBV + e];
            int ix = p.api[(b0 + bi) * NBV + e];
            if (v > best || (v == best && ix < bidx)) { best = v; bidx = ix; }
        }
#pragma unroll
        for (int d = 1; d < 8; d <<= 1) {
            float ov = __shfl_xor(best, d, 8);
            int oi = __shfl_xor(bidx, d, 8);
            if (ov > best || (ov == best && oi < bidx)) { best = ov; bidx = oi; }
        }
        yv0 = __builtin_amdgcn_readlane(bidx, 0);
        yv1 = __builtin_amdgcn_readlane(bidx, 8);
        yv2 = __builtin_amdgcn_readlane(bidx, 16);
        yv3 = __builtin_amdgcn_readlane(bidx, 24);
        yv4 = __builtin_amdgcn_readlane(bidx, 32);
        yv5 = __builtin_amdgcn_readlane(bidx, 40);
        yv6 = __builtin_amdgcn_readlane(bidx, 48);
        yv7 = __builtin_amdgcn_readlane(bidx, 56);
    }
    int yA = (bg == 0) ? yv0 : (bg == 1) ? yv2 : (bg == 2) ? yv4 : yv6;
    int yB = (bg == 0) ? yv1 : (bg == 1) ? yv3 : (bg == 2) ? yv5 : yv7;
    const float* embA = p.emb + (size_t)yA * EE;
    const float* embB = p.emb + (size_t)yB * EE;

    float acc[4][2];
#pragma unroll
    for (int i = 0; i < 4; ++i) { acc[i][0] = 0.f; acc[i][1] = 0.f; }
    float* R = &lds[wu * GSTR];

    for (int ch = 0; ch < 6; ++ch) {
        int kg0 = wu * 192 + ch * 32;   // [0,768): <256 emb, else h
#pragma unroll
        for (int i = 0; i < 8; ++i) {
            int f4 = i * 64 + l;
            int r = f4 >> 3;
            int c4 = (f4 & 7) * 4;
            int j = uc * 16 + (r & 15) + 512 * (r >> 4);
            float4 w;
            if (kg0 < 256)
                w = *(const float4*)&p.Wih[(size_t)j * 768 + 512 + kg0 + c4];
            else
                w = *(const float4*)&p.Whh[(size_t)j * 512 + (kg0 - 256) + c4];
            R[(c4 + 0) * 68 + r] = w.x;
            R[(c4 + 1) * 68 + r] = w.y;
            R[(c4 + 2) * 68 + r] = w.z;
            R[(c4 + 3) * 68 + r] = w.w;
        }
        if (kg0 < 256) {
#pragma unroll 4
            for (int kk = 0; kk < 32; ++kk) {
                float4 wv = *(const float4*)&R[kk * 68 + js * 4];
                float f0 = embA[kg0 + kk];
                float f1 = embB[kg0 + kk];
                float w4[4] = {wv.x, wv.y, wv.z, wv.w};
#pragma unroll
                for (int i = 0; i < 4; ++i) {
                    acc[i][0] = fmaf(w4[i], f0, acc[i][0]);
                    acc[i][1] = fmaf(w4[i], f1, acc[i][1]);
                }
            }
        } else {
#pragma unroll 4
            for (int kk = 0; kk < 32; ++kk) {
                float4 wv = *(const float4*)&R[kk * 68 + js * 4];
                float2 hv = *(const float2*)&fCur[(768 + kg0 - 256 + kk) * BB + b0 + bg * 2];
                float w4[4] = {wv.x, wv.y, wv.z, wv.w};
#pragma unroll
                for (int i = 0; i < 4; ++i) {
                    acc[i][0] = fmaf(w4[i], hv.x, acc[i][0]);
                    acc[i][1] = fmaf(w4[i], hv.y, acc[i][1]);
                }
            }
        }
    }
#pragma unroll
    for (int i = 0; i < 4; ++i) {
        int r = js * 4 + i;
        *(float2*)&R[r * 8 + bg * 2] = make_float2(acc[i][0], acc[i][1]);
    }
    __syncthreads();

    if (tid < 128) {
        int u = tid & 15;
        int bl = tid >> 4;
        float pre[4];
#pragma unroll
        for (int g = 0; g < 4; ++g) {
            int r = u + 16 * g;
            float s = lds[0 * GSTR + r * 8 + bl] + lds[1 * GSTR + r * 8 + bl] +
                      lds[2 * GSTR + r * 8 + bl] + lds[3 * GSTR + r * 8 + bl];
            int j = uc * 16 + u + 512 * g;
            pre[g] = s + p.gzT[(size_t)j * BB + b0 + bl];
        }
        float ig = sigf(pre[0]);
        float fg = sigf(pre[1]);
        float gg = tanhf(pre[2]);
        float og = sigf(pre[3]);
        int u_g = uc * 16 + u;
        int b = b0 + bl;
        float cp = cCur[b * HH + u_g];
        float cn = fg * cp + ig * gg;
        float hn = og * tanhf(cn);
        cNext[b * HH + u_g] = cn;
        fNext[(768 + u_g) * BB + b] = hn;
    }
    if (uc == 0) {
        int yv[8] = {yv0, yv1, yv2, yv3, yv4, yv5, yv6, yv7};
#pragma unroll
        for (int i = 0; i < 8; ++i)
            fNext[(512 + tid) * BB + b0 + i] = p.emb[(size_t)yv[i] * EE + tid];
    }
    __syncthreads();
}

// ---------------------------------------------------------------------------
// logits: 1000 jobs, 32 vocab rows each. 4 waves k-split 320. Lane owns
// 2 v x 8 b. W tile transposed-staged per-wave (stride 38: 2-way, free).
// Epilogue: cross-wave reduce, bias, store, per-job argmax partial.
// ---------------------------------------------------------------------------
__device__ void logits_job(const P& p, int t, int job, float* lds, int tid, int l, int wu) {
    const float* feat = (t & 1) ? p.fA : p.fB;   // fNext of this step
    const int v0 = job * 32;
    const int vs = l & 15;
    const int bg = l >> 4;
    float* R = &lds[wu * LSTR];

    float acc[2][8];
#pragma unroll
    for (int i = 0; i < 2; ++i)
#pragma unroll
        for (int q = 0; q < 8; ++q) acc[i][q] = 0.f;

    for (int ch = 0; ch < 10; ++ch) {
        int kg0 = wu * 320 + ch * 32;
#pragma unroll
        for (int i = 0; i < 4; ++i) {
            int f4 = i * 64 + l;
            int r = f4 >> 3;              // 0..31
            int c4 = (f4 & 7) * 4;
            float4 w = *(const float4*)&p.Wout[(size_t)(v0 + r) * KDIM + kg0 + c4];
            R[(c4 + 0) * 38 + r] = w.x;
            R[(c4 + 1) * 38 + r] = w.y;
            R[(c4 + 2) * 38 + r] = w.z;
            R[(c4 + 3) * 38 + r] = w.w;
        }
#pragma unroll 4
        for (int kk = 0; kk < 32; ++kk) {
            float2 wv = *(const float2*)&R[kk * 38 + vs * 2];
            const float* fp = &feat[(kg0 + kk) * BB + bg * 8];
            float4 fa = *(const float4*)fp;
            float4 fb = *(const float4*)(fp + 4);
            float f8[8] = {fa.x, fa.y, fa.z, fa.w, fb.x, fb.y, fb.z, fb.w};
#pragma unroll
            for (int q = 0; q < 8; ++q) {
                acc[0][q] = fmaf(wv.x, f8[q], acc[0][q]);
                acc[1][q] = fmaf(wv.y, f8[q], acc[1][q]);
            }
        }
    }
#pragma unroll
    for (int i = 0; i < 2; ++i) {
        int r = vs * 2 + i;
        *(float4*)&R[r * 36 + bg * 8] = make_float4(acc[i][0], acc[i][1], acc[i][2], acc[i][3]);
        *(float4*)&R[r * 36 + bg * 8 + 4] = make_float4(acc[i][4], acc[i][5], acc[i][6], acc[i][7]);
    }
    __syncthreads();

    {
        int r = tid & 31;
        int bq = tid >> 5;   // 0..7, 4 b each
        float sv[4];
#pragma unroll
        for (int m = 0; m < 4; ++m) {
            int b = bq * 4 + m;
            sv[m] = lds[0 * LSTR + r * 36 + b] + lds[1 * LSTR + r * 36 + b] +
                    lds[2 * LSTR + r * 36 + b] + lds[3 * LSTR + r * 36 + b] +
                    p.bout[v0 + r];
        }
        if (p.use_staged) {
#pragma unroll
            for (int m = 0; m < 4; ++m)
                p.staged[((size_t)t * BB + bq * 4 + m) * VV + v0 + r] = sv[m];
        } else {
#pragma unroll
            for (int m = 0; m < 4; ++m)
                p.out[((size_t)(bq * 4 + m) * VV + v0 + r) * TT + t] = sv[m];
        }
#pragma unroll
        for (int m = 0; m < 4; ++m) {
            float bv = sv[m];
            int bi = v0 + r;
#pragma unroll
            for (int d = 1; d < 32; d <<= 1) {
                float ov = __shfl_xor(bv, d, 32);
                int oi = __shfl_xor(bi, d, 32);
                if (ov > bv || (ov == bv && oi < bi)) { bv = ov; bi = oi; }
            }
            if (r == 0) {
                p.apv[(bq * 4 + m) * NBV + job] = bv;
                p.api[(bq * 4 + m) * NBV + job] = bi;
            }
        }
    }
    __syncthreads();
}

// ---------------------------------------------------------------------------
// trans: 16000 jobs. staged (T,B,V) -> out (B,V,T), coalesced both sides.
// ---------------------------------------------------------------------------
__device__ void trans_job(const P& p, int job, float* lds, int tid) {
    int b = job / 500;
    int v0 = (job % 500) * 64;
    int vl = tid & 63;
    int tq = tid >> 6;
#pragma unroll
    for (int i = 0; i < 16; ++i) {
        int tt = tq * 16 + i;
        lds[tt * 65 + vl] = p.staged[((size_t)tt * BB + b) * VV + v0 + vl];
    }
    __syncthreads();
    int v2 = tid >> 2;
    int t0 = (tid & 3) * 16;
#pragma unroll
    for (int q = 0; q < 4; ++q) {
        float4 val;
        val.x = lds[(t0 + q * 4 + 0) * 65 + v2];
        val.y = lds[(t0 + q * 4 + 1) * 65 + v2];
        val.z = lds[(t0 + q * 4 + 2) * 65 + v2];
        val.w = lds[(t0 + q * 4 + 3) * 65 + v2];
        *(float4*)&p.out[((size_t)b * VV + v0 + v2) * TT + t0 + q * 4] = val;
    }
    __syncthreads();
}

// ---------------------------------------------------------------------------
// Cooperative mega-kernel: one launch, grid.sync between phases.
// ---------------------------------------------------------------------------
__global__ __launch_bounds__(256, 4) void mega(P p) {
    cg::grid_group grid = cg::this_grid();
    __shared__ float lds[LDSF];
    const int tid = threadIdx.x;
    const int l = tid & 63;
    const int wu = tid >> 6;
    const int blk = blockIdx.x;
    const int nblk = gridDim.x;

    for (int job = blk; job < 64; job += nblk) init_job(p, job, tid);
    grid.sync();
    for (int job = blk; job < 32; job += nblk) pre_job(p, job, lds, tid, l, wu);
    grid.sync();

    for (int t = 0; t < TT; ++t) {
        for (int job = blk; job < NGJ; job += nblk) gates_job(p, t, job, lds, tid, l, wu);
        grid.sync();
        for (int job = blk; job < NBV; job += nblk) logits_job(p, t, job, lds, tid, l, wu);
        grid.sync();
    }
    if (p.use_staged)
        for (int job = blk; job < BB * 500; job += nblk) trans_job(p, job, lds, tid);
}

// ---------------------------------------------------------------------------
// Fallback thin kernels (same device code) if cooperative launch unavailable.
// ---------------------------------------------------------------------------
__global__ __launch_bounds__(256) void kg_init(P p) { init_job(p, blockIdx.x, threadIdx.x); }
__global__ __launch_bounds__(256) void kg_pre(P p) {
    __shared__ float lds[LDSF];
    pre_job(p, blockIdx.x, lds, threadIdx.x, threadIdx.x & 63, threadIdx.x >> 6);
}
__global__ __launch_bounds__(256) void kg_gates(P p, int t) {
    __shared__ float lds[LDSF];
    gates_job(p, t, blockIdx.x, lds, threadIdx.x, threadIdx.x & 63, threadIdx.x >> 6);
}
__global__ __launch_bounds__(256) void kg_logits(P p, int t) {
    __shared__ float lds[LDSF];
    logits_job(p, t, blockIdx.x, lds, threadIdx.x, threadIdx.x & 63, threadIdx.x >> 6);
}
__global__ __launch_bounds__(256) void kg_trans(P p) {
    __shared__ float lds[LDSF];
    trans_job(p, blockIdx.x, lds, threadIdx.x);
}

// ---------------------------------------------------------------------------
extern "C" void kernel_launch(void* const* d_in, const int* in_sizes, int n_in,
                              void* d_out, int out_size, void* d_ws, size_t ws_size,
                              hipStream_t stream) {
    const size_t stagedFloats = (size_t)TT * BB * VV;   // 65,536,000
    const size_t smallBytes = (2 * (size_t)KDIM * BB + 2 * (size_t)BB * HH +
                               4 * (size_t)HH * BB + (size_t)BB * NBV) * 4 +
                              (size_t)BB * NBV * sizeof(int) + 256;
    int use_staged = (ws_size >= stagedFloats * 4 + smallBytes) ? 1 : 0;

    char* w = (char*)d_ws;
    size_t off = use_staged ? stagedFloats * 4 : 0;
    float* staged = (float*)d_ws;
    float* fA = (float*)(w + off); off += (size_t)KDIM * BB * 4;
    float* fB = (float*)(w + off); off += (size_t)KDIM * BB * 4;
    float* cA = (float*)(w + off); off += (size_t)BB * HH * 4;
    float* cB = (float*)(w + off); off += (size_t)BB * HH * 4;
    float* gzT = (float*)(w + off); off += (size_t)4 * HH * BB * 4;
    float* apv = (float*)(w + off); off += (size_t)BB * NBV * 4;
    int* api = (int*)(w + off);

    P pp;
    pp.y0 = (const int*)d_in[0];
    pp.h0 = (const float*)d_in[1];
    pp.c0 = (const float*)d_in[2];
    pp.emb = (const float*)d_in[3];
    pp.Wih = (const float*)d_in[4];
    pp.Whh = (const float*)d_in[5];
    pp.bih = (const float*)d_in[6];
    pp.bhh = (const float*)d_in[7];
    pp.Wout = (const float*)d_in[8];
    pp.bout = (const float*)d_in[9];
    pp.out = (float*)d_out;
    pp.staged = staged;
    pp.use_staged = use_staged;
    pp.fA = fA; pp.fB = fB; pp.cA = cA; pp.cB = cB; pp.gzT = gzT;
    pp.apv = apv; pp.api = api;

    int dev = 0;
    (void)hipGetDevice(&dev);
    int nCU = 0;
    if (hipDeviceGetAttribute(&nCU, hipDeviceAttributeMultiprocessorCount, dev) != hipSuccess || nCU <= 0)
        nCU = 256;
    int maxb = 0;
    if (hipOccupancyMaxActiveBlocksPerMultiprocessor(&maxb, mega, 256, 0) != hipSuccess)
        maxb = 0;
    long long grid = (long long)maxb * nCU;
    if (grid > NBV) grid = NBV;

    hipError_t err = hipErrorUnknown;
    if (grid >= 64) {
        void* args[] = {(void*)&pp};
        err = hipLaunchCooperativeKernel(mega, dim3((unsigned)grid), dim3(256), args, 0, stream);
    }
    if (err != hipSuccess) {
        // fallback: serialized multi-kernel path (same device code)
        kg_init<<<64, 256, 0, stream>>>(pp);
        kg_pre<<<32, 256, 0, stream>>>(pp);
        for (int t = 0; t < TT; ++t) {
            kg_gates<<<NGJ, 256, 0, stream>>>(pp, t);
            kg_logits<<<NBV, 256, 0, stream>>>(pp, t);
        }
        if (use_staged) kg_trans<<<BB * 500, 256, 0, stream>>>(pp);
    }
}